// Round 1
// baseline (7135.237 us; speedup 1.0000x reference)
//
#include <hip/hip_runtime.h>
#include <hip/hip_bf16.h>

typedef __bf16 bf16;
typedef __bf16 bf16x8 __attribute__((ext_vector_type(8)));
typedef __bf16 bf16x4 __attribute__((ext_vector_type(4)));
typedef float  f32x4  __attribute__((ext_vector_type(4)));

// ---------------------------------------------------------------------------
// GEMM: C[M,N] = A[M,K] * B[N,K]^T (+bias[N]).  fp32 in/out, bf16 MFMA inside.
// 64x64 tile, 4 waves, each wave a 32x32 patch of 16x16x32 fragments.
// ---------------------------------------------------------------------------
__global__ __launch_bounds__(256, 2)
void gemm_bt_kernel(const float* __restrict__ A, const float* __restrict__ B,
                    const float* __restrict__ bias, float* __restrict__ C,
                    int M, int N, int K, int lda, int ldb, int ldc)
{
    __shared__ bf16 As[64][72];   // +8 pad (144B stride) to break bank alias
    __shared__ bf16 Bs[64][72];
    const int tid = threadIdx.x;
    const long bm = (long)blockIdx.y * 64;
    const long bn = (long)blockIdx.x * 64;
    const int w  = tid >> 6;
    const int l  = tid & 63;
    const int wm = (w >> 1) * 32, wn = (w & 1) * 32;
    const int lr = l & 15, lk = (l >> 4) * 8;

    const int srow = tid >> 2;
    const int scol = (tid & 3) * 16;
    const float* Ap = A + (bm + srow) * (long)lda + scol;
    const float* Bp = B + (bn + srow) * (long)ldb + scol;

    f32x4 acc[2][2];
    #pragma unroll
    for (int mi = 0; mi < 2; ++mi)
        #pragma unroll
        for (int ni = 0; ni < 2; ++ni)
            acc[mi][ni] = f32x4{0.f, 0.f, 0.f, 0.f};

    for (int kt = 0; kt < K; kt += 64) {
        #pragma unroll
        for (int i = 0; i < 16; i += 4) {
            float4 av = *reinterpret_cast<const float4*>(Ap + kt + i);
            float4 bv = *reinterpret_cast<const float4*>(Bp + kt + i);
            bf16x4 ac; ac[0] = (bf16)av.x; ac[1] = (bf16)av.y; ac[2] = (bf16)av.z; ac[3] = (bf16)av.w;
            bf16x4 bc; bc[0] = (bf16)bv.x; bc[1] = (bf16)bv.y; bc[2] = (bf16)bv.z; bc[3] = (bf16)bv.w;
            *reinterpret_cast<bf16x4*>(&As[srow][scol + i]) = ac;
            *reinterpret_cast<bf16x4*>(&Bs[srow][scol + i]) = bc;
        }
        __syncthreads();
        #pragma unroll
        for (int kk = 0; kk < 64; kk += 32) {
            bf16x8 a0 = *reinterpret_cast<const bf16x8*>(&As[wm +  0 + lr][kk + lk]);
            bf16x8 a1 = *reinterpret_cast<const bf16x8*>(&As[wm + 16 + lr][kk + lk]);
            bf16x8 b0 = *reinterpret_cast<const bf16x8*>(&Bs[wn +  0 + lr][kk + lk]);
            bf16x8 b1 = *reinterpret_cast<const bf16x8*>(&Bs[wn + 16 + lr][kk + lk]);
            acc[0][0] = __builtin_amdgcn_mfma_f32_16x16x32_bf16(a0, b0, acc[0][0], 0, 0, 0);
            acc[0][1] = __builtin_amdgcn_mfma_f32_16x16x32_bf16(a0, b1, acc[0][1], 0, 0, 0);
            acc[1][0] = __builtin_amdgcn_mfma_f32_16x16x32_bf16(a1, b0, acc[1][0], 0, 0, 0);
            acc[1][1] = __builtin_amdgcn_mfma_f32_16x16x32_bf16(a1, b1, acc[1][1], 0, 0, 0);
        }
        __syncthreads();
    }
    // C/D layout (m89-verified): col = lane&15, row = (lane>>4)*4 + reg
    const int crow = wm + (l >> 4) * 4;
    const int ccol = wn + (l & 15);
    #pragma unroll
    for (int mi = 0; mi < 2; ++mi)
        #pragma unroll
        for (int ni = 0; ni < 2; ++ni) {
            long col = bn + ccol + ni * 16;
            float bv = bias ? bias[col] : 0.0f;
            #pragma unroll
            for (int r = 0; r < 4; ++r) {
                long row = bm + crow + mi * 16 + r;
                C[row * (long)ldc + col] = acc[mi][ni][r] + bv;
            }
        }
}

// ---------------------------------------------------------------------------
// Sequential SSM scan: h_t = tanh(h_{t-1} A^T + xB_t), 4 batches, 1024 steps.
// 56 blocks x 512 threads. Block owns 16 rows of A (in registers: 28 f32/thr).
// Cross-block sync: 8-deep ring of h buffers in ws; "data is the flag" --
// buffers are pre/re-filled with NaN sentinel (0xFFFFFFFF) and readers poll
// the data itself with agent-scope atomic loads (bypass non-coherent L2s).
// h (4x896) staged into LDS each step; fp32 throughout (numerically critical).
// ---------------------------------------------------------------------------
#define SENT 0xFFFFFFFFu

__global__ __launch_bounds__(512)
void ssm_scan_kernel(const float* __restrict__ Amat,
                     const float* __restrict__ xB,     // (4,1024,896)
                     float* __restrict__ hs,           // (4,1024,896)
                     unsigned int* __restrict__ hbuf)  // 8 * 3584 f32-bits
{
    __shared__ float hS[3584];
    const int tid = threadIdx.x;
    const int bi  = blockIdx.x;
    const int kq  = tid & 31;      // 32 k-slices of 28
    const int rg  = tid >> 5;      // 16 rows per block
    const int row = bi * 16 + rg;

    float4 areg[7];
    {
        const float4* Ap = reinterpret_cast<const float4*>(Amat + (long)row * 896 + kq * 28);
        #pragma unroll
        for (int j = 0; j < 7; ++j) areg[j] = Ap[j];
    }

    for (int t = 1; t <= 1024; ++t) {
        // ---- stage h_state[t-1]: poll data until no sentinel ----
        {
            const unsigned int* src = hbuf + ((t - 1) & 7) * 3584;
            #pragma unroll
            for (int j = 0; j < 7; ++j) {
                int idx = tid + j * 512;
                unsigned int v = __hip_atomic_load(&src[idx], __ATOMIC_RELAXED, __HIP_MEMORY_SCOPE_AGENT);
                while (v == SENT) {
                    __builtin_amdgcn_s_sleep(1);
                    v = __hip_atomic_load(&src[idx], __ATOMIC_RELAXED, __HIP_MEMORY_SCOPE_AGENT);
                }
                hS[idx] = __builtin_bit_cast(float, v);
            }
        }
        // ---- re-sentinel our slice of buffer (t-2) for its reuse at t+6 ----
        if (t >= 2 && tid < 64) {
            unsigned int* rst = hbuf + ((t - 2) & 7) * 3584;
            int b = tid >> 4, r = tid & 15;
            __hip_atomic_store(&rst[b * 896 + bi * 16 + r], SENT, __ATOMIC_RELAXED, __HIP_MEMORY_SCOPE_AGENT);
        }
        __syncthreads();

        // ---- partial dot: this thread's 28-wide k-slice, 4 batches ----
        const float4* h0p = reinterpret_cast<const float4*>(hS +    0 + kq * 28);
        const float4* h1p = reinterpret_cast<const float4*>(hS +  896 + kq * 28);
        const float4* h2p = reinterpret_cast<const float4*>(hS + 1792 + kq * 28);
        const float4* h3p = reinterpret_cast<const float4*>(hS + 2688 + kq * 28);
        float a0 = 0, a1 = 0, a2 = 0, a3 = 0;
        #pragma unroll
        for (int j = 0; j < 7; ++j) {
            float4 a = areg[j];
            float4 v0 = h0p[j]; a0 += a.x*v0.x + a.y*v0.y + a.z*v0.z + a.w*v0.w;
            float4 v1 = h1p[j]; a1 += a.x*v1.x + a.y*v1.y + a.z*v1.z + a.w*v1.w;
            float4 v2 = h2p[j]; a2 += a.x*v2.x + a.y*v2.y + a.z*v2.z + a.w*v2.w;
            float4 v3 = h3p[j]; a3 += a.x*v3.x + a.y*v3.y + a.z*v3.z + a.w*v3.w;
        }
        // reduce over the 32 kq lanes (stays within 32-lane half of the wave)
        a0 += __shfl_xor(a0, 16); a1 += __shfl_xor(a1, 16); a2 += __shfl_xor(a2, 16); a3 += __shfl_xor(a3, 16);
        a0 += __shfl_xor(a0,  8); a1 += __shfl_xor(a1,  8); a2 += __shfl_xor(a2,  8); a3 += __shfl_xor(a3,  8);
        a0 += __shfl_xor(a0,  4); a1 += __shfl_xor(a1,  4); a2 += __shfl_xor(a2,  4); a3 += __shfl_xor(a3,  4);
        a0 += __shfl_xor(a0,  2); a1 += __shfl_xor(a1,  2); a2 += __shfl_xor(a2,  2); a3 += __shfl_xor(a3,  2);
        a0 += __shfl_xor(a0,  1); a1 += __shfl_xor(a1,  1); a2 += __shfl_xor(a2,  1); a3 += __shfl_xor(a3,  1);

        if (kq == 0) {
            unsigned int* dst = hbuf + (t & 7) * 3584;
            const long so = (long)(t - 1) * 896 + row;
            float z[4] = { a0 + xB[so],            a1 + xB[so +  917504],
                           a2 + xB[so + 1835008],  a3 + xB[so + 2752512] };
            #pragma unroll
            for (int b = 0; b < 4; ++b) {
                float zz = fminf(fmaxf(z[b], -15.f), 15.f);
                float e  = __expf(2.f * zz);
                float h  = (e - 1.f) / (e + 1.f);
                __hip_atomic_store(&dst[b * 896 + row], __builtin_bit_cast(unsigned int, h),
                                   __ATOMIC_RELAXED, __HIP_MEMORY_SCOPE_AGENT);
                hs[(long)b * 917504 + so] = h;   // plain store; flushed at kernel end
            }
        }
        __syncthreads();  // drains vmcnt: orders resets/stores before next step
    }
}

// ---------------------------------------------------------------------------
// Attention: per block = (b, head, 16-row q-chunk). Two-pass, scores in LDS,
// K/V staged as bf16 chunks. fp32 softmax. Round-1 VALU implementation.
// ---------------------------------------------------------------------------
__global__ __launch_bounds__(256)
void attn_kernel(const float* __restrict__ qkv, float* __restrict__ ctx)
{
    __shared__ float qS[16][56];
    __shared__ float sS[16][1025];   // +1 pad: bank = row
    __shared__ bf16  kvS[64][60];    // +4 pad: 120B stride
    const int tid = threadIdx.x;
    const int bid = blockIdx.x;
    const int qc = bid & 63;
    const int h  = (bid >> 6) & 15;
    const int b  = bid >> 10;
    const long base = (long)b * 1024 * 2688;
    const int q0 = qc * 16;
    const int hoff = h * 56;

    for (int idx = tid; idx < 16 * 56; idx += 256) {
        int r = idx / 56, d = idx - r * 56;
        qS[r][d] = qkv[base + (long)(q0 + r) * 2688 + hoff + d] * 0.13363062095621f; // 1/sqrt(56)
    }
    const int qg = tid >> 5, kg = tid & 31;
    const int r0 = 2 * qg, r1 = r0 + 1, c0 = 2 * kg, c1 = c0 + 1;

    for (int kt = 0; kt < 16; ++kt) {
        __syncthreads();
        for (int idx = tid; idx < 64 * 56; idx += 256) {
            int r = idx / 56, d = idx - r * 56;
            kvS[r][d] = (bf16)qkv[base + (long)(kt * 64 + r) * 2688 + 896 + hoff + d];
        }
        __syncthreads();
        float a00 = 0, a01 = 0, a10 = 0, a11 = 0;
        #pragma unroll 8
        for (int d = 0; d < 56; ++d) {
            float qa = qS[r0][d], qb = qS[r1][d];
            float ka = (float)kvS[c0][d], kb = (float)kvS[c1][d];
            a00 += qa * ka; a01 += qa * kb; a10 += qb * ka; a11 += qb * kb;
        }
        sS[r0][kt * 64 + c0] = a00; sS[r0][kt * 64 + c1] = a01;
        sS[r1][kt * 64 + c0] = a10; sS[r1][kt * 64 + c1] = a11;
    }
    __syncthreads();
    {   // softmax over k (1024) per row; 16 lanes per row
        const int r = tid >> 4, seg = tid & 15;
        float mx = -1e30f;
        for (int k = seg; k < 1024; k += 16) mx = fmaxf(mx, sS[r][k]);
        mx = fmaxf(mx, __shfl_xor(mx, 8)); mx = fmaxf(mx, __shfl_xor(mx, 4));
        mx = fmaxf(mx, __shfl_xor(mx, 2)); mx = fmaxf(mx, __shfl_xor(mx, 1));
        float sum = 0;
        for (int k = seg; k < 1024; k += 16) { float e = __expf(sS[r][k] - mx); sS[r][k] = e; sum += e; }
        sum += __shfl_xor(sum, 8); sum += __shfl_xor(sum, 4);
        sum += __shfl_xor(sum, 2); sum += __shfl_xor(sum, 1);
        float inv = 1.0f / sum;
        for (int k = seg; k < 1024; k += 16) sS[r][k] *= inv;
    }
    // PV: thread = (q = tid&15, dslot = tid>>4), d = dslot + 16j
    const int q = tid & 15, ds = tid >> 4;
    float o0 = 0, o1 = 0, o2 = 0, o3 = 0;
    for (int kt = 0; kt < 16; ++kt) {
        __syncthreads();
        for (int idx = tid; idx < 64 * 56; idx += 256) {
            int r = idx / 56, d = idx - r * 56;
            kvS[r][d] = (bf16)qkv[base + (long)(kt * 64 + r) * 2688 + 1792 + hoff + d];
        }
        __syncthreads();
        #pragma unroll 4
        for (int kk = 0; kk < 64; ++kk) {
            float p = sS[q][kt * 64 + kk];
            o0 += p * (float)kvS[kk][ds];
            o1 += p * (float)kvS[kk][ds + 16];
            o2 += p * (float)kvS[kk][ds + 32];
            if (ds < 8) o3 += p * (float)kvS[kk][ds + 48];
        }
    }
    float* cp = ctx + ((long)b * 1024 + q0 + q) * 896 + hoff;
    cp[ds] = o0; cp[ds + 16] = o1; cp[ds + 32] = o2;
    if (ds < 8) cp[ds + 48] = o3;
}

// ---------------------------------------------------------------------------
// Two LayerNorms (ssm_out, attn_out) -> packed "combined" buffer (4096 x 1792)
// One row per 64-lane wave, 4 waves/block.
// ---------------------------------------------------------------------------
__global__ __launch_bounds__(256)
void ln2_kernel(const float* __restrict__ s_in, const float* __restrict__ a_in,
                const float* __restrict__ gs, const float* __restrict__ bs,
                const float* __restrict__ ga, const float* __restrict__ ba,
                float* __restrict__ comb)
{
    const int wv = threadIdx.x >> 6, ln = threadIdx.x & 63;
    const long row = (long)blockIdx.x * 4 + wv;
    const bool is_a = (blockIdx.y != 0);
    const float* src = (is_a ? a_in : s_in) + row * 896;
    float v[14]; float sum = 0, sq = 0;
    #pragma unroll
    for (int j = 0; j < 14; ++j) { v[j] = src[ln + j * 64]; sum += v[j]; sq += v[j] * v[j]; }
    #pragma unroll
    for (int off = 32; off >= 1; off >>= 1) { sum += __shfl_xor(sum, off); sq += __shfl_xor(sq, off); }
    const float mean = sum * (1.0f / 896.0f);
    const float var  = sq * (1.0f / 896.0f) - mean * mean;
    const float inv  = rsqrtf(var + 1e-5f);
    const float* g  = is_a ? ga : gs;
    const float* bb = is_a ? ba : bs;
    float* dst = comb + row * 1792 + (is_a ? 896 : 0);
    #pragma unroll
    for (int j = 0; j < 14; ++j) {
        int i = ln + j * 64;
        dst[i] = (v[j] - mean) * inv * g[i] + bb[i];
    }
}

// ---------------------------------------------------------------------------
// Gates (2-way softmax of fused @ gate_w^T + gate_b) and final mix -> d_out
// 16 rows per block, 16 lanes per row.
// ---------------------------------------------------------------------------
__global__ __launch_bounds__(256)
void gate_mix_kernel(const float* __restrict__ fused, const float* __restrict__ gw,
                     const float* __restrict__ gb, const float* __restrict__ comb,
                     float* __restrict__ out)
{
    const int tid = threadIdx.x;
    const int seg = tid & 15;
    const long row = (long)blockIdx.x * 16 + (tid >> 4);
    const float* fr = fused + row * 896;
    float d0 = 0, d1 = 0;
    for (int i = seg; i < 896; i += 16) {
        float f = fr[i];
        d0 += f * gw[i];
        d1 += f * gw[896 + i];
    }
    #pragma unroll
    for (int off = 8; off >= 1; off >>= 1) { d0 += __shfl_xor(d0, off); d1 += __shfl_xor(d1, off); }
    float l0 = d0 + gb[0], l1 = d1 + gb[1];
    float m = fmaxf(l0, l1);
    float e0 = __expf(l0 - m), e1 = __expf(l1 - m);
    float inv = 1.0f / (e0 + e1);
    float g0 = e0 * inv, g1 = e1 * inv;
    const float* cr = comb + row * 1792;
    float* orow = out + row * 896;
    for (int i = seg; i < 896; i += 16)
        orow[i] = g0 * cr[i] + g1 * cr[896 + i];
}

// ---------------------------------------------------------------------------
extern "C" void kernel_launch(void* const* d_in, const int* in_sizes, int n_in,
                              void* d_out, int out_size, void* d_ws, size_t ws_size,
                              hipStream_t stream)
{
    (void)in_sizes; (void)n_in; (void)out_size; (void)ws_size;
    const float* x         = (const float*)d_in[0];
    const float* Amat      = (const float*)d_in[1];
    const float* Bm        = (const float*)d_in[2];
    const float* Cm        = (const float*)d_in[3];
    const float* ssm_in_w  = (const float*)d_in[4];
    const float* ssm_in_b  = (const float*)d_in[5];
    const float* ssm_out_w = (const float*)d_in[6];
    const float* ssm_out_b = (const float*)d_in[7];
    const float* qkv_w     = (const float*)d_in[8];
    const float* qkv_b     = (const float*)d_in[9];
    const float* attn_w    = (const float*)d_in[10];
    const float* attn_b    = (const float*)d_in[11];
    const float* proj_w    = (const float*)d_in[12];
    const float* proj_b    = (const float*)d_in[13];
    const float* ln_sg     = (const float*)d_in[14];
    const float* ln_sb     = (const float*)d_in[15];
    const float* ln_ag     = (const float*)d_in[16];
    const float* ln_ab     = (const float*)d_in[17];
    const float* fuse_w    = (const float*)d_in[18];
    const float* fuse_b    = (const float*)d_in[19];
    const float* gate_w    = (const float*)d_in[20];
    const float* gate_b    = (const float*)d_in[21];

    float* ws = (float*)d_ws;
    const long S0 = 0;          // xp, later ys           (4096x896)
    const long S1 = 3670016;    // xB, later t1           (4096x896)
    const long S2 = 7340032;    // qkv                    (4096x2688)
    const long S3 = 18350080;   // hs, later attn_out     (4096x896)
    const long S4 = 22020096;   // ssm_out, later fused   (4096x896)
    const long S5 = 25690112;   // combined               (4096x1792)
    const long S6 = 33030144;   // ctx                    (4096x896)
    const long S7 = 36700160;   // h ring buffers (8x3584)

    dim3 g896(14, 64), gqkv(42, 64);

    // h-ring init: slot0 = h0 = 0; slots 1..7 = NaN sentinel (0xFF bytes)
    hipMemsetAsync(ws + S7, 0x00, 3584 * sizeof(float), stream);
    hipMemsetAsync(ws + S7 + 3584, 0xFF, 7 * 3584 * sizeof(float), stream);

    // SSM input path: xp = x@ssm_in_w^T + b ; xB = xp@Bm^T
    gemm_bt_kernel<<<g896, 256, 0, stream>>>(x, ssm_in_w, ssm_in_b, ws + S0, 4096, 896, 896, 896, 896, 896);
    gemm_bt_kernel<<<g896, 256, 0, stream>>>(ws + S0, Bm, nullptr, ws + S1, 4096, 896, 896, 896, 896, 896);
    // qkv = x@qkv_w^T + b
    gemm_bt_kernel<<<gqkv, 256, 0, stream>>>(x, qkv_w, qkv_b, ws + S2, 4096, 2688, 896, 896, 896, 2688);
    // sequential scan -> hs
    ssm_scan_kernel<<<56, 512, 0, stream>>>(Amat, ws + S1, ws + S3, (unsigned int*)(ws + S7));
    // ys = hs@Cm^T ; ssm_out = ys@ssm_out_w^T + b
    gemm_bt_kernel<<<g896, 256, 0, stream>>>(ws + S3, Cm, nullptr, ws + S0, 4096, 896, 896, 896, 896, 896);
    gemm_bt_kernel<<<g896, 256, 0, stream>>>(ws + S0, ssm_out_w, ssm_out_b, ws + S4, 4096, 896, 896, 896, 896, 896);
    // attention: ctx ; t1 = ctx@attn_w^T + b ; attn_out = t1@proj_w^T + b
    attn_kernel<<<4096, 256, 0, stream>>>(ws + S2, ws + S6);
    gemm_bt_kernel<<<g896, 256, 0, stream>>>(ws + S6, attn_w, attn_b, ws + S1, 4096, 896, 896, 896, 896, 896);
    gemm_bt_kernel<<<g896, 256, 0, stream>>>(ws + S1, proj_w, proj_b, ws + S3, 4096, 896, 896, 896, 896, 896);
    // layernorms -> combined [ssm_g | attn_g]
    ln2_kernel<<<dim3(1024, 2), 256, 0, stream>>>(ws + S4, ws + S3, ln_sg, ln_sb, ln_ag, ln_ab, ws + S5);
    // fused = combined(K=1792) @ fuse_w[:, :1792]^T + b  (zero third kills cols 1792+)
    gemm_bt_kernel<<<g896, 256, 0, stream>>>(ws + S5, fuse_w, fuse_b, ws + S4, 4096, 896, 1792, 1792, 2688, 896);
    // gates + mix -> out
    gate_mix_kernel<<<256, 256, 0, stream>>>(ws + S4, gate_w, gate_b, ws + S5, (float*)d_out);
}